// Round 1
// 138.713 us; speedup vs baseline: 1.1484x; 1.1484x over previous
//
#include <hip/hip_runtime.h>
#include <hip/hip_bf16.h>

typedef __attribute__((ext_vector_type(8))) short bf16x8;
typedef __attribute__((ext_vector_type(4))) float f32x4;

static __device__ __forceinline__ f32x4 mfma16(bf16x8 a, bf16x8 b, f32x4 c) {
    return __builtin_amdgcn_mfma_f32_16x16x32_bf16(a, b, c, 0, 0, 0);
}

#define LOG2E 1.44269504f

// ---------------- Kernel 1: QKV projection ----------------
// x: (2, 256, 4096) f32 ; w: (768, 256) f32
// qb[bh][n][64], kb[bh][m][64] bf16 ; vt[bh][64][m] bf16
__global__ __launch_bounds__(256, 4) void qkv_kernel(
    const float* __restrict__ x, const float* __restrict__ w,
    __hip_bfloat16* __restrict__ qb, __hip_bfloat16* __restrict__ kb,
    __hip_bfloat16* __restrict__ vt)
{
    alignas(16) __shared__ __hip_bfloat16 sA[64 * 72];   // w tile [o][c]
    alignas(16) __shared__ __hip_bfloat16 sB[64 * 72];   // x tile transposed [n][c]
    const int nb = blockIdx.x * 64;
    const int ob = blockIdx.y * 64;
    const int b  = blockIdx.z;
    const int tid  = threadIdx.x;
    const int lane = tid & 63;
    const int wv   = tid >> 6;
    const int quad = lane >> 4;
    const int l16  = lane & 15;

    f32x4 acc[4];
    for (int i = 0; i < 4; i++) acc[i] = (f32x4)0.f;

    for (int k0 = 0; k0 < 256; k0 += 64) {
        __syncthreads();
        {   // A: w tile, float4 loads, b128 LDS stores
            const int o = tid >> 2, c0 = (tid & 3) << 4;
            const float* srcw = w + (ob + o) * 256 + k0 + c0;
            union { bf16x8 v; __hip_bfloat16 h[8]; } u0, u1;
            #pragma unroll
            for (int i = 0; i < 2; i++) {
                float4 f = *(const float4*)(srcw + i * 4);
                u0.h[4*i+0] = __float2bfloat16(f.x); u0.h[4*i+1] = __float2bfloat16(f.y);
                u0.h[4*i+2] = __float2bfloat16(f.z); u0.h[4*i+3] = __float2bfloat16(f.w);
            }
            #pragma unroll
            for (int i = 0; i < 2; i++) {
                float4 f = *(const float4*)(srcw + 8 + i * 4);
                u1.h[4*i+0] = __float2bfloat16(f.x); u1.h[4*i+1] = __float2bfloat16(f.y);
                u1.h[4*i+2] = __float2bfloat16(f.z); u1.h[4*i+3] = __float2bfloat16(f.w);
            }
            *(bf16x8*)&sA[o * 72 + c0]     = u0.v;
            *(bf16x8*)&sA[o * 72 + c0 + 8] = u1.v;
        }
        {   // B: x tile, float4 loads, transposed scalar LDS stores
            const int c = tid >> 2, n0 = (tid & 3) << 4;
            const float* srcx = x + ((size_t)b * 256 + k0 + c) * 4096 + nb + n0;
            #pragma unroll
            for (int i = 0; i < 4; i++) {
                float4 f = *(const float4*)(srcx + i * 4);
                sB[(n0 + 4*i + 0) * 72 + c] = __float2bfloat16(f.x);
                sB[(n0 + 4*i + 1) * 72 + c] = __float2bfloat16(f.y);
                sB[(n0 + 4*i + 2) * 72 + c] = __float2bfloat16(f.z);
                sB[(n0 + 4*i + 3) * 72 + c] = __float2bfloat16(f.w);
            }
        }
        __syncthreads();
        const __hip_bfloat16* aRow = &sA[(16 * wv + l16) * 72];
        #pragma unroll
        for (int ks = 0; ks < 2; ks++) {
            bf16x8 af = *(const bf16x8*)&aRow[ks * 32 + quad * 8];
            #pragma unroll
            for (int ct = 0; ct < 4; ct++) {
                bf16x8 bfv = *(const bf16x8*)&sB[(16 * ct + l16) * 72 + ks * 32 + quad * 8];
                acc[ct] = mfma16(af, bfv, acc[ct]);
            }
        }
    }
    // ---- epilogue: vectorized stores ----
    if (ob < 512) {
        // q/k: 4 consecutive output channels (r) = 4 consecutive d -> b64 store
        #pragma unroll
        for (int ct = 0; ct < 4; ct++) {
            int n = nb + 16 * ct + l16;
            int o0 = ob + 16 * wv + quad * 4;        // 4-aligned, single 64-block
            union { short4 s; __hip_bfloat16 hh[4]; } u;
            #pragma unroll
            for (int r = 0; r < 4; r++) u.hh[r] = __float2bfloat16(acc[ct][r]);
            int oo = o0 & 255;
            int bhh = b * 4 + (oo >> 6), d = oo & 63;
            __hip_bfloat16* dst = (o0 >= 256 ? kb : qb) + ((size_t)bhh * 4096 + n) * 64 + d;
            *(short4*)dst = u.s;
        }
    } else {
        // v: transpose 16x64 per-wave tile through LDS, then contiguous b128 stores
        __syncthreads();   // all MFMA reads of sA/sB done
        #pragma unroll
        for (int ct = 0; ct < 4; ct++)
            #pragma unroll
            for (int r = 0; r < 4; r++)
                sA[(16 * wv + quad * 4 + r) * 72 + 16 * ct + l16] = __float2bfloat16(acc[ct][r]);
        // wave-private tile rows 16wv..16wv+15: no barrier needed (in-wave RAW)
        int o2 = (ob - 512) + 16 * wv + l16;
        int bhh = b * 4 + (o2 >> 6), d = o2 & 63;
        __hip_bfloat16* dst = vt + ((size_t)bhh * 64 + d) * 4096 + nb + 16 * quad;
        const __hip_bfloat16* srcl = &sA[(16 * wv + l16) * 72 + 16 * quad];
        *(bf16x8*)dst       = *(const bf16x8*)srcl;
        *(bf16x8*)(dst + 8) = *(const bf16x8*)(srcl + 8);
    }
}

// ---------------- Kernel 2: fused flash attention + rel-pos bias ----------------
// 8 waves = 2 q-groups (32 rows) x 4 key-slices (32 keys of the 128 staged per j).
// Swapped QK^T (mfma(K,Q) -> S^T): each lane holds P for q-row l16 only -> P stays
// in registers. PV uses a key-slot permutation slot(8*quad+4*kt+r) <-> key(16*kt+
// 4*quad+r) applied consistently to P register packing AND the LDS V^T layout
// (MFMA contraction is permutation-invariant when both operands agree).
__global__ __launch_bounds__(512, 4) void attn_kernel(
    const __hip_bfloat16* __restrict__ qb, const __hip_bfloat16* __restrict__ kb,
    const __hip_bfloat16* __restrict__ vt, const float* __restrict__ hrel,
    const float* __restrict__ wrel, float* __restrict__ out)
{
    alignas(16) __shared__ __hip_bfloat16 sU[18432];     // 36864 B overlay region
    alignas(16) __shared__ __hip_bfloat16 sRH[64 * 66];  // persistent rh bias [q][h']

    const int h    = blockIdx.x;
    const int bh   = blockIdx.y;
    const int tid  = threadIdx.x;
    const int lane = tid & 63;
    const int wv   = tid >> 6;      // 0..7
    const int qg   = wv >> 2;       // q rows qg*32..+31
    const int kg   = wv & 3;        // key slice kg*32..+31 within staged 128
    const int quad = lane >> 4;
    const int l16  = lane & 15;

    // prologue overlay
    __hip_bfloat16* sQ   = sU;               // 64x72
    __hip_bfloat16* sW   = sU + 64 * 72;     // 128x72 (wrel, row 127 zeroed)
    __hip_bfloat16* sHRs = sU + 192 * 72;    // 64x72 (shifted hrel)
    __hip_bfloat16* sRWt = sU;               // 64x68 gather scratch (overlays sQ)
    // main-loop overlay
    __hip_bfloat16* sKb  = sU;               // [128][72]
    __hip_bfloat16* sVb  = sU + 128 * 72;    // [64][136] slot-permuted V^T

    // ---- prologue staging ----
    {   // Q: 64x64 bf16 contiguous
        int r = tid >> 3, d8 = (tid & 7) * 8;
        *(bf16x8*)&sQ[r * 72 + d8] =
            *(const bf16x8*)&qb[(((size_t)bh * 4096 + h * 64 + r)) * 64 + d8];
    }
    {   // wrel: 127x64 f32 -> bf16 (row 127 zero)
        int r = tid >> 2, c0 = (tid & 3) << 4;
        union { bf16x8 v; __hip_bfloat16 h8[8]; } u0, u1;
        #pragma unroll
        for (int i = 0; i < 2; i++) {
            float4 f = (r < 127) ? *(const float4*)&wrel[r * 64 + c0 + 4*i] : float4{0,0,0,0};
            u0.h8[4*i+0] = __float2bfloat16(f.x); u0.h8[4*i+1] = __float2bfloat16(f.y);
            u0.h8[4*i+2] = __float2bfloat16(f.z); u0.h8[4*i+3] = __float2bfloat16(f.w);
        }
        #pragma unroll
        for (int i = 0; i < 2; i++) {
            float4 f = (r < 127) ? *(const float4*)&wrel[r * 64 + c0 + 8 + 4*i] : float4{0,0,0,0};
            u1.h8[4*i+0] = __float2bfloat16(f.x); u1.h8[4*i+1] = __float2bfloat16(f.y);
            u1.h8[4*i+2] = __float2bfloat16(f.z); u1.h8[4*i+3] = __float2bfloat16(f.w);
        }
        *(bf16x8*)&sW[r * 72 + c0]     = u0.v;
        *(bf16x8*)&sW[r * 72 + c0 + 8] = u1.v;
    }
    {   // hrel rows [63-h, 127-h) -> sHRs[hp][d]
        int r = tid >> 3, c0 = (tid & 7) * 8;
        union { bf16x8 v; __hip_bfloat16 h8[8]; } u0;
        #pragma unroll
        for (int i = 0; i < 2; i++) {
            float4 f = *(const float4*)&hrel[(63 - h + r) * 64 + c0 + 4*i];
            u0.h8[4*i+0] = __float2bfloat16(f.x); u0.h8[4*i+1] = __float2bfloat16(f.y);
            u0.h8[4*i+2] = __float2bfloat16(f.z); u0.h8[4*i+3] = __float2bfloat16(f.w);
        }
        *(bf16x8*)&sHRs[r * 72 + c0] = u0.v;
    }
    __syncthreads();

    // fragments: gather frags (g-mapped) + main Q frags (qg-mapped)
    const int g    = wv & 3;
    const int half = wv >> 2;
    const __hip_bfloat16* aRow = &sQ[(16 * g + l16) * 72];
    bf16x8 qf0 = *(const bf16x8*)&aRow[quad * 8];
    bf16x8 qf1 = *(const bf16x8*)&aRow[32 + quad * 8];
    bf16x8 qm[2][2];
    #pragma unroll
    for (int qt = 0; qt < 2; qt++) {
        const __hip_bfloat16* qr = &sQ[(qg * 32 + 16 * qt + l16) * 72];
        qm[qt][0] = *(const bf16x8*)&qr[quad * 8];
        qm[qt][1] = *(const bf16x8*)&qr[32 + quad * 8];
    }
    __syncthreads();   // all frags read before sRWt overwrites sQ

    // rw gather: X[w][rr] = Q . wrel[rr]; scatter wp = rr + w - 63 -> sRWt[w][wp]
    {
        const int rbase = half * 64;
        #pragma unroll
        for (int ct = 0; ct < 4; ct++) {
            int rr = rbase + 16 * ct + l16;
            f32x4 a = (f32x4)0.f;
            a = mfma16(qf0, *(const bf16x8*)&sW[rr * 72 + quad * 8], a);
            a = mfma16(qf1, *(const bf16x8*)&sW[rr * 72 + 32 + quad * 8], a);
            #pragma unroll
            for (int r = 0; r < 4; r++) {
                int ww = 16 * g + quad * 4 + r;
                int wp = rr + ww - 63;
                if (wp >= 0 && wp < 64) sRWt[ww * 68 + wp] = __float2bfloat16(a[r]);
            }
        }
    }
    // rh bias (waves 0-3): sRH[w][h'] = Q . sHRs[h']
    if (half == 0) {
        #pragma unroll
        for (int ct = 0; ct < 4; ct++) {
            f32x4 a = (f32x4)0.f;
            a = mfma16(qf0, *(const bf16x8*)&sHRs[(16 * ct + l16) * 72 + quad * 8], a);
            a = mfma16(qf1, *(const bf16x8*)&sHRs[(16 * ct + l16) * 72 + 32 + quad * 8], a);
            #pragma unroll
            for (int r = 0; r < 4; r++)
                sRH[(16 * g + quad * 4 + r) * 66 + 16 * ct + l16] = __float2bfloat16(a[r]);
        }
    }
    __syncthreads();

    // hoist rw bias: j-invariant per wave. rwp[qt][kt].h[r] = rw[q][32*(kg&1)+16*kt+4*quad+r]
    union S4 { short4 s; __hip_bfloat16 h[4]; };
    S4 rwp[2][2];
    #pragma unroll
    for (int qt = 0; qt < 2; qt++)
        #pragma unroll
        for (int kt = 0; kt < 2; kt++)
            rwp[qt][kt].s = *(const short4*)&sRWt[(qg * 32 + 16 * qt + l16) * 68
                                                  + 32 * (kg & 1) + 16 * kt + 4 * quad];
    __syncthreads();   // sRWt/sW/sHRs dead; main loop owns sU

    f32x4 oacc[2][4];
    #pragma unroll
    for (int qt = 0; qt < 2; qt++)
        #pragma unroll
        for (int dt = 0; dt < 4; dt++) oacc[qt][dt] = (f32x4)0.f;
    float lsum[2] = {0.f, 0.f};

    const __hip_bfloat16* ksrc = kb + (size_t)bh * 4096 * 64;
    const __hip_bfloat16* vsrc = vt + (size_t)bh * 64 * 4096;

    // staging maps (512 threads stage 128 keys x 64 d of K and V per j)
    const int skey = tid >> 2, sd16 = (tid & 3) * 16;          // K: [key][d]
    const int svd  = tid >> 3, sq3  = tid & 7;                 // V: [d][key]
    const int skg  = sq3 >> 1, st   = sq3 & 1;
    __hip_bfloat16* stK = &sKb[skey * 72 + sd16];
    __hip_bfloat16* stV = &sVb[svd * 136 + skg * 32 + st * 4];
    const __hip_bfloat16* gK = ksrc + (size_t)skey * 64 + sd16;
    const __hip_bfloat16* gV = vsrc + (size_t)svd * 4096 + sq3 * 16;

    bf16x8 pk0, pk1, pv0, pv1;
    pk0 = *(const bf16x8*)(gK);
    pk1 = *(const bf16x8*)(gK + 8);
    pv0 = *(const bf16x8*)(gV);
    pv1 = *(const bf16x8*)(gV + 8);

    const __hip_bfloat16* kr0  = &sKb[(kg * 32 + l16) * 72 + quad * 8];
    const __hip_bfloat16* vrow = &sVb[l16 * 136 + kg * 32 + quad * 8];
    const __hip_bfloat16* rh0  = &sRH[(qg * 32 + l16) * 66];
    const __hip_bfloat16* rh1  = &sRH[(qg * 32 + 16 + l16) * 66];

    for (int j = 0; j < 32; j++) {
        // stage: K rows linear; V slot-permuted (key 16kt+4q+r -> slot 8q+4kt+r)
        *(bf16x8*)(stK)     = pk0;
        *(bf16x8*)(stK + 8) = pk1;
        {
            union { bf16x8 v; short4 q[2]; } ua, ub;
            ua.v = pv0; ub.v = pv1;
            *(short4*)(stV)      = ua.q[0];
            *(short4*)(stV + 8)  = ua.q[1];
            *(short4*)(stV + 16) = ub.q[0];
            *(short4*)(stV + 24) = ub.q[1];
        }
        __syncthreads();
        if (j < 31) {   // prefetch next 128-key tile
            size_t kb0 = (size_t)(j + 1) * 128;
            pk0 = *(const bf16x8*)(gK + kb0 * 64);
            pk1 = *(const bf16x8*)(gK + kb0 * 64 + 8);
            pv0 = *(const bf16x8*)(gV + kb0);
            pv1 = *(const bf16x8*)(gV + kb0 + 8);
        }

        // K fragments (shared across both q-tiles)
        bf16x8 kf00 = *(const bf16x8*)(kr0);
        bf16x8 kf01 = *(const bf16x8*)(kr0 + 32);
        bf16x8 kf10 = *(const bf16x8*)(kr0 + 16 * 72);
        bf16x8 kf11 = *(const bf16x8*)(kr0 + 16 * 72 + 32);

        const int hp = 2 * j + (kg >> 1);
        bf16x8 pa[2];
        #pragma unroll
        for (int qt = 0; qt < 2; qt++) {
            // S^T = mfma(K, Q): lane -> S[key=kg*32+16*kt+4*quad+r][q=qg*32+16*qt+l16]
            f32x4 s0 = (f32x4)0.f, s1 = (f32x4)0.f;
            s0 = mfma16(kf00, qm[qt][0], s0);
            s0 = mfma16(kf01, qm[qt][1], s0);
            s1 = mfma16(kf10, qm[qt][0], s1);
            s1 = mfma16(kf11, qm[qt][1], s1);
            float rhb = LOG2E * __bfloat162float((qt ? rh1 : rh0)[hp]);
            union { bf16x8 v; __hip_bfloat16 hh[8]; } pu;
            #pragma unroll
            for (int r = 0; r < 4; r++) {
                float p = __builtin_amdgcn_exp2f(
                    fmaf(s0[r], 0.125f * LOG2E,
                         fmaf(__bfloat162float(rwp[qt][0].h[r]), LOG2E, rhb)));
                lsum[qt] += p;
                pu.hh[r] = __float2bfloat16(p);
            }
            #pragma unroll
            for (int r = 0; r < 4; r++) {
                float p = __builtin_amdgcn_exp2f(
                    fmaf(s1[r], 0.125f * LOG2E,
                         fmaf(__bfloat162float(rwp[qt][1].h[r]), LOG2E, rhb)));
                lsum[qt] += p;
                pu.hh[4 + r] = __float2bfloat16(p);
            }
            pa[qt] = pu.v;   // slot e=4*kt+r matches V LDS slot layout
        }

        // O += P V  (P in registers; V slot-permuted b128 frags)
        #pragma unroll
        for (int dt = 0; dt < 4; dt++) {
            bf16x8 vf = *(const bf16x8*)(vrow + dt * 16 * 136);
            oacc[0][dt] = mfma16(pa[0], vf, oacc[0][dt]);
            oacc[1][dt] = mfma16(pa[1], vf, oacc[1][dt]);
        }
        __syncthreads();
    }

    // quads hold disjoint keys of the slice: reduce lsum across quads
    #pragma unroll
    for (int qt = 0; qt < 2; qt++) {
        lsum[qt] += __shfl_xor(lsum[qt], 16, 64);
        lsum[qt] += __shfl_xor(lsum[qt], 32, 64);
    }

    // combine the 4 key-slices: kg 1..3 write partials, kg 0 accumulates
    float* obuf  = (float*)sU;          // [2 qg][64 d][36] (q-major rows, padded)
    float* slbuf = obuf + 4608;         // [2 qg][64 q]
    for (int rnd = 1; rnd < 4; rnd++) {
        if (kg == rnd) {
            #pragma unroll
            for (int qt = 0; qt < 2; qt++)
                #pragma unroll
                for (int dt = 0; dt < 4; dt++)
                    *(f32x4*)&obuf[qg * 2304 + (16 * dt + l16) * 36 + 16 * qt + 4 * quad]
                        = oacc[qt][dt];
            if (quad == 0) {
                slbuf[qg * 64 + l16]      = lsum[0];
                slbuf[qg * 64 + 16 + l16] = lsum[1];
            }
        }
        __syncthreads();
        if (kg == 0) {
            #pragma unroll
            for (int qt = 0; qt < 2; qt++)
                #pragma unroll
                for (int dt = 0; dt < 4; dt++)
                    oacc[qt][dt] += *(const f32x4*)&obuf[qg * 2304 + (16 * dt + l16) * 36
                                                          + 16 * qt + 4 * quad];
            lsum[0] += slbuf[qg * 64 + l16];
            lsum[1] += slbuf[qg * 64 + 16 + l16];
        }
        __syncthreads();
    }

    if (kg == 0) {
        // redistribute row-sums (lane l16 holds row l16; acc regs hold rows 4*quad+r)
        if (quad == 0) {
            slbuf[qg * 64 + l16]      = lsum[0];
            slbuf[qg * 64 + 16 + l16] = lsum[1];
        }
        const int b = bh >> 2, head = bh & 3;
        #pragma unroll
        for (int qt = 0; qt < 2; qt++) {
            f32x4 lv;
            #pragma unroll
            for (int r = 0; r < 4; r++)
                lv[r] = 1.f / slbuf[qg * 64 + 16 * qt + 4 * quad + r];
            #pragma unroll
            for (int dt = 0; dt < 4; dt++) {
                f32x4 o = oacc[qt][dt] * lv;
                int dv = 16 * dt + l16;
                int q0 = qg * 32 + 16 * qt + 4 * quad;
                *(f32x4*)&out[((size_t)(b * 256 + head * 64 + dv)) * 4096 + h * 64 + q0] = o;
            }
        }
    }
}

extern "C" void kernel_launch(void* const* d_in, const int* in_sizes, int n_in,
                              void* d_out, int out_size, void* d_ws, size_t ws_size,
                              hipStream_t stream) {
    const float* x     = (const float*)d_in[0];
    const float* qkv_w = (const float*)d_in[1];
    const float* hrel  = (const float*)d_in[2];
    const float* wrel  = (const float*)d_in[3];
    float* out = (float*)d_out;

    __hip_bfloat16* qb = (__hip_bfloat16*)d_ws;
    __hip_bfloat16* kb = qb + (size_t)8 * 4096 * 64;
    __hip_bfloat16* vt = kb + (size_t)8 * 4096 * 64;

    qkv_kernel<<<dim3(64, 12, 2), 256, 0, stream>>>(x, qkv_w, qb, kb, vt);
    attn_kernel<<<dim3(64, 8), 512, 0, stream>>>(qb, kb, vt, hrel, wrel, out);
}

// Round 2
// 131.547 us; speedup vs baseline: 1.2110x; 1.0545x over previous
//
#include <hip/hip_runtime.h>
#include <hip/hip_bf16.h>

typedef __attribute__((ext_vector_type(8))) short bf16x8;
typedef __attribute__((ext_vector_type(4))) float f32x4;

static __device__ __forceinline__ f32x4 mfma16(bf16x8 a, bf16x8 b, f32x4 c) {
    return __builtin_amdgcn_mfma_f32_16x16x32_bf16(a, b, c, 0, 0, 0);
}
// async global->LDS DMA, 16 B per lane; LDS dest = wave-uniform base + lane*16
static __device__ __forceinline__ void gll16(const void* g, void* l) {
    __builtin_amdgcn_global_load_lds(
        (const __attribute__((address_space(1))) unsigned int*)g,
        (__attribute__((address_space(3))) unsigned int*)l, 16, 0, 0);
}

#define LOG2E 1.44269504f

// ---------------- Kernel 1: QKV projection ----------------
// x: (2, 256, 4096) f32 ; w: (768, 256) f32
// qb[bh][n][64] linear bf16
// kb[bh][key][64] bf16, SWIZZLED: elem d stored at d ^ ((key&7)<<3)
// vt[bh][64][4096] bf16, slot-PERMUTED within 32-key groups (key 16kt+4q+r -> 8q+4kt+r)
//                        then SWIZZLED: pos p stored at p ^ ((d&7)<<3)
__global__ __launch_bounds__(256, 4) void qkv_kernel(
    const float* __restrict__ x, const float* __restrict__ w,
    __hip_bfloat16* __restrict__ qb, __hip_bfloat16* __restrict__ kb,
    __hip_bfloat16* __restrict__ vt)
{
    alignas(16) __shared__ __hip_bfloat16 sA[64 * 72];   // w tile [o][c]
    alignas(16) __shared__ __hip_bfloat16 sB[64 * 72];   // x tile transposed [n][c], c XOR-swizzled
    const int nb = blockIdx.x * 64;
    const int ob = blockIdx.y * 64;
    const int b  = blockIdx.z;
    const int tid  = threadIdx.x;
    const int lane = tid & 63;
    const int wv   = tid >> 6;
    const int quad = lane >> 4;
    const int l16  = lane & 15;

    f32x4 acc[4];
    for (int i = 0; i < 4; i++) acc[i] = (f32x4)0.f;

    for (int k0 = 0; k0 < 256; k0 += 64) {
        __syncthreads();
        {   // A: w tile, float4 loads, b128 LDS stores
            const int o = tid >> 2, c0 = (tid & 3) << 4;
            const float* srcw = w + (ob + o) * 256 + k0 + c0;
            union { bf16x8 v; __hip_bfloat16 h[8]; } u0, u1;
            #pragma unroll
            for (int i = 0; i < 2; i++) {
                float4 f = *(const float4*)(srcw + i * 4);
                u0.h[4*i+0] = __float2bfloat16(f.x); u0.h[4*i+1] = __float2bfloat16(f.y);
                u0.h[4*i+2] = __float2bfloat16(f.z); u0.h[4*i+3] = __float2bfloat16(f.w);
            }
            #pragma unroll
            for (int i = 0; i < 2; i++) {
                float4 f = *(const float4*)(srcw + 8 + i * 4);
                u1.h[4*i+0] = __float2bfloat16(f.x); u1.h[4*i+1] = __float2bfloat16(f.y);
                u1.h[4*i+2] = __float2bfloat16(f.z); u1.h[4*i+3] = __float2bfloat16(f.w);
            }
            *(bf16x8*)&sA[o * 72 + c0]     = u0.v;
            *(bf16x8*)&sA[o * 72 + c0 + 8] = u1.v;
        }
        {   // B: x tile, float4 loads, transposed scalar LDS stores.
            // XOR swizzle c ^= 16*((n>>4)&3) spreads the 16-row stride across banks
            // (write was 8-way conflicted: 16*72 elem stride == 0 mod 32 banks).
            const int c = tid >> 2, n0 = (tid & 3) << 4;
            const int csw = c ^ ((tid & 3) * 16);
            const float* srcx = x + ((size_t)b * 256 + k0 + c) * 4096 + nb + n0;
            #pragma unroll
            for (int i = 0; i < 4; i++) {
                float4 f = *(const float4*)(srcx + i * 4);
                sB[(n0 + 4*i + 0) * 72 + csw] = __float2bfloat16(f.x);
                sB[(n0 + 4*i + 1) * 72 + csw] = __float2bfloat16(f.y);
                sB[(n0 + 4*i + 2) * 72 + csw] = __float2bfloat16(f.z);
                sB[(n0 + 4*i + 3) * 72 + csw] = __float2bfloat16(f.w);
            }
        }
        __syncthreads();
        const __hip_bfloat16* aRow = &sA[(16 * wv + l16) * 72];
        #pragma unroll
        for (int ks = 0; ks < 2; ks++) {
            bf16x8 af = *(const bf16x8*)&aRow[ks * 32 + quad * 8];
            #pragma unroll
            for (int ct = 0; ct < 4; ct++) {
                // matching constant XOR per (ct): logical c run stays consecutive
                bf16x8 bfv = *(const bf16x8*)&sB[(16 * ct + l16) * 72
                                                 + ((ks * 32 + quad * 8) ^ (ct * 16))];
                acc[ct] = mfma16(af, bfv, acc[ct]);
            }
        }
    }
    // ---- epilogue ----
    if (ob < 512) {
        // q: linear; k: bank-swizzle baked into global layout
        #pragma unroll
        for (int ct = 0; ct < 4; ct++) {
            int n = nb + 16 * ct + l16;
            int o0 = ob + 16 * wv + quad * 4;
            union { short4 s; __hip_bfloat16 hh[4]; } u;
            #pragma unroll
            for (int r = 0; r < 4; r++) u.hh[r] = __float2bfloat16(acc[ct][r]);
            int oo = o0 & 255;
            int bhh = b * 4 + (oo >> 6), d = oo & 63;
            if (o0 < 256) {
                *(short4*)(qb + ((size_t)bhh * 4096 + n) * 64 + d) = u.s;
            } else {
                *(short4*)(kb + ((size_t)bhh * 4096 + n) * 64 + (d ^ ((n & 7) << 3))) = u.s;
            }
        }
    } else {
        // v: transpose 16x64 per-wave tile through LDS, then slot-permuted + swizzled stores
        __syncthreads();   // all MFMA reads of sA/sB done
        #pragma unroll
        for (int ct = 0; ct < 4; ct++)
            #pragma unroll
            for (int r = 0; r < 4; r++)
                sA[(16 * wv + quad * 4 + r) * 72 + 16 * ct + l16] = __float2bfloat16(acc[ct][r]);
        // wave-private tile rows: in-wave RAW, no barrier needed
        int o2 = (ob - 512) + 16 * wv + l16;
        int bhh = b * 4 + (o2 >> 6), d = o2 & 63;
        const __hip_bfloat16* srcl = &sA[(16 * wv + l16) * 72 + 16 * quad];
        __hip_bfloat16* vrow = vt + ((size_t)bhh * 64 + d) * 4096;
        const int kt = quad & 1;
        const int gbase = nb + (quad >> 1) * 32;
        const int dsw = (d & 7) << 3;
        #pragma unroll
        for (int m = 0; m < 4; m++) {
            short4 val = *(const short4*)(srcl + 4 * m);
            int P4 = gbase + 8 * m + 4 * kt;          // slot-permuted position
            *(short4*)(vrow + (P4 ^ dsw)) = val;      // bank swizzle
        }
    }
}

// ---------------- Kernel 2: fused flash attention + rel-pos bias ----------------
// 8 waves = 2 q-groups x 4 key-slices. Swapped QK^T keeps P in registers.
// K/V staged by global_load_lds DMA into double-buffered linear LDS (swizzle baked
// into the global layouts by qkv_kernel): zero staging wave-instructions, one
// barrier per 128-key tile, no prefetch registers.
__global__ __launch_bounds__(512, 4) void attn_kernel(
    const __hip_bfloat16* __restrict__ qb, const __hip_bfloat16* __restrict__ kb,
    const __hip_bfloat16* __restrict__ vt, const float* __restrict__ hrel,
    const float* __restrict__ wrel, float* __restrict__ out)
{
    extern __shared__ __align__(16) char smem[];         // 65536 B: 2 x (16KB K + 16KB V)
    alignas(16) __shared__ __hip_bfloat16 sRH[64 * 66];  // persistent rh bias [q][h']

    const int h    = blockIdx.x;
    const int bh   = blockIdx.y;
    const int tid  = threadIdx.x;
    const int lane = tid & 63;
    const int wv   = tid >> 6;      // 0..7
    const int qg   = wv >> 2;       // q rows qg*32..+31
    const int kg   = wv & 3;        // key slice kg*32..+31 within staged 128
    const int quad = lane >> 4;
    const int l16  = lane & 15;

    // prologue overlay
    __hip_bfloat16* sQ   = (__hip_bfloat16*)smem;            // 64x72
    __hip_bfloat16* sW   = (__hip_bfloat16*)smem + 64 * 72;  // 128x72 (wrel, row 127 zero)
    __hip_bfloat16* sHRs = (__hip_bfloat16*)smem + 192 * 72; // 64x72 (shifted hrel)
    __hip_bfloat16* sRWt = (__hip_bfloat16*)smem;            // 64x68 gather scratch

    // ---- prologue staging ----
    {   // Q: 64x64 bf16 contiguous
        int r = tid >> 3, d8 = (tid & 7) * 8;
        *(bf16x8*)&sQ[r * 72 + d8] =
            *(const bf16x8*)&qb[(((size_t)bh * 4096 + h * 64 + r)) * 64 + d8];
    }
    {   // wrel: 127x64 f32 -> bf16 (row 127 zero)
        int r = tid >> 2, c0 = (tid & 3) << 4;
        union { bf16x8 v; __hip_bfloat16 h8[8]; } u0, u1;
        #pragma unroll
        for (int i = 0; i < 2; i++) {
            float4 f = (r < 127) ? *(const float4*)&wrel[r * 64 + c0 + 4*i] : float4{0,0,0,0};
            u0.h8[4*i+0] = __float2bfloat16(f.x); u0.h8[4*i+1] = __float2bfloat16(f.y);
            u0.h8[4*i+2] = __float2bfloat16(f.z); u0.h8[4*i+3] = __float2bfloat16(f.w);
        }
        #pragma unroll
        for (int i = 0; i < 2; i++) {
            float4 f = (r < 127) ? *(const float4*)&wrel[r * 64 + c0 + 8 + 4*i] : float4{0,0,0,0};
            u1.h8[4*i+0] = __float2bfloat16(f.x); u1.h8[4*i+1] = __float2bfloat16(f.y);
            u1.h8[4*i+2] = __float2bfloat16(f.z); u1.h8[4*i+3] = __float2bfloat16(f.w);
        }
        *(bf16x8*)&sW[r * 72 + c0]     = u0.v;
        *(bf16x8*)&sW[r * 72 + c0 + 8] = u1.v;
    }
    {   // hrel rows [63-h, 127-h) -> sHRs[hp][d]
        int r = tid >> 3, c0 = (tid & 7) * 8;
        union { bf16x8 v; __hip_bfloat16 h8[8]; } u0;
        #pragma unroll
        for (int i = 0; i < 2; i++) {
            float4 f = *(const float4*)&hrel[(63 - h + r) * 64 + c0 + 4*i];
            u0.h8[4*i+0] = __float2bfloat16(f.x); u0.h8[4*i+1] = __float2bfloat16(f.y);
            u0.h8[4*i+2] = __float2bfloat16(f.z); u0.h8[4*i+3] = __float2bfloat16(f.w);
        }
        *(bf16x8*)&sHRs[r * 72 + c0] = u0.v;
    }
    __syncthreads();

    // fragments: gather frags (g-mapped) + main Q frags (qg-mapped)
    const int g    = wv & 3;
    const int half = wv >> 2;
    const __hip_bfloat16* aRow = &sQ[(16 * g + l16) * 72];
    bf16x8 qf0 = *(const bf16x8*)&aRow[quad * 8];
    bf16x8 qf1 = *(const bf16x8*)&aRow[32 + quad * 8];
    bf16x8 qm[2][2];
    #pragma unroll
    for (int qt = 0; qt < 2; qt++) {
        const __hip_bfloat16* qr = &sQ[(qg * 32 + 16 * qt + l16) * 72];
        qm[qt][0] = *(const bf16x8*)&qr[quad * 8];
        qm[qt][1] = *(const bf16x8*)&qr[32 + quad * 8];
    }
    __syncthreads();   // all frags read before sRWt overwrites sQ

    // rw gather: X[w][rr] = Q . wrel[rr]; scatter wp = rr + w - 63 -> sRWt[w][wp]
    {
        const int rbase = half * 64;
        #pragma unroll
        for (int ct = 0; ct < 4; ct++) {
            int rr = rbase + 16 * ct + l16;
            f32x4 a = (f32x4)0.f;
            a = mfma16(qf0, *(const bf16x8*)&sW[rr * 72 + quad * 8], a);
            a = mfma16(qf1, *(const bf16x8*)&sW[rr * 72 + 32 + quad * 8], a);
            #pragma unroll
            for (int r = 0; r < 4; r++) {
                int ww = 16 * g + quad * 4 + r;
                int wp = rr + ww - 63;
                if (wp >= 0 && wp < 64) sRWt[ww * 68 + wp] = __float2bfloat16(a[r]);
            }
        }
    }
    // rh bias (waves 0-3): sRH[w][h'] = Q . sHRs[h']
    if (half == 0) {
        #pragma unroll
        for (int ct = 0; ct < 4; ct++) {
            f32x4 a = (f32x4)0.f;
            a = mfma16(qf0, *(const bf16x8*)&sHRs[(16 * ct + l16) * 72 + quad * 8], a);
            a = mfma16(qf1, *(const bf16x8*)&sHRs[(16 * ct + l16) * 72 + 32 + quad * 8], a);
            #pragma unroll
            for (int r = 0; r < 4; r++)
                sRH[(16 * g + quad * 4 + r) * 66 + 16 * ct + l16] = __float2bfloat16(a[r]);
        }
    }
    __syncthreads();

    // hoist rw bias (j-invariant per wave)
    union S4 { short4 s; __hip_bfloat16 h[4]; };
    S4 rwp[2][2];
    #pragma unroll
    for (int qt = 0; qt < 2; qt++)
        #pragma unroll
        for (int kt = 0; kt < 2; kt++)
            rwp[qt][kt].s = *(const short4*)&sRWt[(qg * 32 + 16 * qt + l16) * 68
                                                  + 32 * (kg & 1) + 16 * kt + 4 * quad];
    __syncthreads();   // prologue LDS dead; DMA may now own smem

    // per-thread DMA source addresses (swizzle baked into global layout)
    const char* kT = (const char*)kb + (size_t)bh * 524288 + wv * 1024 + lane * 16;
    const char* vT = (const char*)vt + (size_t)bh * 524288
                     + (size_t)(wv * 4 + quad) * 8192 + l16 * 16;

    // stage tile 0 into buf0
    gll16(kT,           smem + wv * 1024);
    gll16(kT + 8192,    smem + 8192 + wv * 1024);
    gll16(vT,           smem + 16384 + wv * 1024);
    gll16(vT + 262144,  smem + 24576 + wv * 1024);
    __syncthreads();   // drains vmcnt: tile 0 resident

    f32x4 oacc[2][4];
    #pragma unroll
    for (int qt = 0; qt < 2; qt++)
        #pragma unroll
        for (int dt = 0; dt < 4; dt++) oacc[qt][dt] = (f32x4)0.f;
    float lsum[2] = {0.f, 0.f};

    // fragment read offsets (XOR de-swizzle; conflict-free b128)
    const int krowOff = (kg * 32 + l16) * 128;
    const int sw  = (l16 & 7) << 4;
    const int kA  = (quad * 16) ^ sw;
    const int kB  = (64 + quad * 16) ^ sw;
    const int vOff = 16384 + l16 * 256 + ((kg * 64 + quad * 16) ^ sw);

    const __hip_bfloat16* rh0 = &sRH[(qg * 32 + l16) * 66];
    const __hip_bfloat16* rh1 = &sRH[(qg * 32 + 16 + l16) * 66];

    for (int j = 0; j < 32; j++) {
        const char* buf = smem + (j & 1) * 32768;
        if (j < 31) {   // issue next-tile DMA into the other buffer (freed by last barrier)
            char* nbuf = smem + ((j + 1) & 1) * 32768;
            const char* gk = kT + (size_t)(j + 1) * 16384;
            gll16(gk,          nbuf + wv * 1024);
            gll16(gk + 8192,   nbuf + 8192 + wv * 1024);
            const char* gv = vT + (size_t)(j + 1) * 256;
            gll16(gv,          nbuf + 16384 + wv * 1024);
            gll16(gv + 262144, nbuf + 24576 + wv * 1024);
        }

        // K fragments (shared across both q-tiles)
        const char* kr = buf + krowOff;
        bf16x8 kf00 = *(const bf16x8*)(kr + kA);
        bf16x8 kf01 = *(const bf16x8*)(kr + kB);
        bf16x8 kf10 = *(const bf16x8*)(kr + 2048 + kA);
        bf16x8 kf11 = *(const bf16x8*)(kr + 2048 + kB);

        const int hp = 2 * j + (kg >> 1);
        bf16x8 pa[2];
        #pragma unroll
        for (int qt = 0; qt < 2; qt++) {
            // S^T = mfma(K, Q): lane -> S[key=kg*32+16*kt+4*quad+r][q=qg*32+16*qt+l16]
            f32x4 s0 = (f32x4)0.f, s1 = (f32x4)0.f;
            s0 = mfma16(kf00, qm[qt][0], s0);
            s0 = mfma16(kf01, qm[qt][1], s0);
            s1 = mfma16(kf10, qm[qt][0], s1);
            s1 = mfma16(kf11, qm[qt][1], s1);
            float rhb = LOG2E * __bfloat162float((qt ? rh1 : rh0)[hp]);
            union { bf16x8 v; __hip_bfloat16 hh[8]; } pu;
            #pragma unroll
            for (int r = 0; r < 4; r++) {
                float p = __builtin_amdgcn_exp2f(
                    fmaf(s0[r], 0.125f * LOG2E,
                         fmaf(__bfloat162float(rwp[qt][0].h[r]), LOG2E, rhb)));
                lsum[qt] += p;
                pu.hh[r] = __float2bfloat16(p);
            }
            #pragma unroll
            for (int r = 0; r < 4; r++) {
                float p = __builtin_amdgcn_exp2f(
                    fmaf(s1[r], 0.125f * LOG2E,
                         fmaf(__bfloat162float(rwp[qt][1].h[r]), LOG2E, rhb)));
                lsum[qt] += p;
                pu.hh[4 + r] = __float2bfloat16(p);
            }
            pa[qt] = pu.v;   // slot e=4*kt+r matches vt slot layout
        }

        // O += P V  (P in registers; V slot-permuted b128 frags)
        #pragma unroll
        for (int dt = 0; dt < 4; dt++) {
            bf16x8 vf = *(const bf16x8*)(buf + vOff + dt * 4096);
            oacc[0][dt] = mfma16(pa[0], vf, oacc[0][dt]);
            oacc[1][dt] = mfma16(pa[1], vf, oacc[1][dt]);
        }
        __syncthreads();   // drains this wave's DMA (next tile) + releases buffers
    }

    // quads hold disjoint keys of the slice: reduce lsum across quads
    #pragma unroll
    for (int qt = 0; qt < 2; qt++) {
        lsum[qt] += __shfl_xor(lsum[qt], 16, 64);
        lsum[qt] += __shfl_xor(lsum[qt], 32, 64);
    }

    // combine the 4 key-slices: kg 1..3 write partials, kg 0 accumulates
    float* obuf  = (float*)smem;        // [2 qg][64 d][36]
    float* slbuf = obuf + 4608;         // [2 qg][64 q]
    for (int rnd = 1; rnd < 4; rnd++) {
        if (kg == rnd) {
            #pragma unroll
            for (int qt = 0; qt < 2; qt++)
                #pragma unroll
                for (int dt = 0; dt < 4; dt++)
                    *(f32x4*)&obuf[qg * 2304 + (16 * dt + l16) * 36 + 16 * qt + 4 * quad]
                        = oacc[qt][dt];
            if (quad == 0) {
                slbuf[qg * 64 + l16]      = lsum[0];
                slbuf[qg * 64 + 16 + l16] = lsum[1];
            }
        }
        __syncthreads();
        if (kg == 0) {
            #pragma unroll
            for (int qt = 0; qt < 2; qt++)
                #pragma unroll
                for (int dt = 0; dt < 4; dt++)
                    oacc[qt][dt] += *(const f32x4*)&obuf[qg * 2304 + (16 * dt + l16) * 36
                                                          + 16 * qt + 4 * quad];
            lsum[0] += slbuf[qg * 64 + l16];
            lsum[1] += slbuf[qg * 64 + 16 + l16];
        }
        __syncthreads();
    }

    if (kg == 0) {
        if (quad == 0) {
            slbuf[qg * 64 + l16]      = lsum[0];
            slbuf[qg * 64 + 16 + l16] = lsum[1];
        }
        const int b = bh >> 2, head = bh & 3;
        #pragma unroll
        for (int qt = 0; qt < 2; qt++) {
            f32x4 lv;
            #pragma unroll
            for (int r = 0; r < 4; r++)
                lv[r] = 1.f / slbuf[qg * 64 + 16 * qt + 4 * quad + r];
            #pragma unroll
            for (int dt = 0; dt < 4; dt++) {
                f32x4 o = oacc[qt][dt] * lv;
                int dv = 16 * dt + l16;
                int q0 = qg * 32 + 16 * qt + 4 * quad;
                *(f32x4*)&out[((size_t)(b * 256 + head * 64 + dv)) * 4096 + h * 64 + q0] = o;
            }
        }
    }
}

extern "C" void kernel_launch(void* const* d_in, const int* in_sizes, int n_in,
                              void* d_out, int out_size, void* d_ws, size_t ws_size,
                              hipStream_t stream) {
    const float* x     = (const float*)d_in[0];
    const float* qkv_w = (const float*)d_in[1];
    const float* hrel  = (const float*)d_in[2];
    const float* wrel  = (const float*)d_in[3];
    float* out = (float*)d_out;

    __hip_bfloat16* qb = (__hip_bfloat16*)d_ws;
    __hip_bfloat16* kb = qb + (size_t)8 * 4096 * 64;
    __hip_bfloat16* vt = kb + (size_t)8 * 4096 * 64;

    qkv_kernel<<<dim3(64, 12, 2), 256, 0, stream>>>(x, qkv_w, qb, kb, vt);
    attn_kernel<<<dim3(64, 8), 512, 65536, stream>>>(qb, kb, vt, hrel, wrel, out);
}

// Round 3
// 125.394 us; speedup vs baseline: 1.2704x; 1.0491x over previous
//
#include <hip/hip_runtime.h>
#include <hip/hip_bf16.h>

typedef __attribute__((ext_vector_type(8))) short bf16x8;
typedef __attribute__((ext_vector_type(4))) float f32x4;

static __device__ __forceinline__ f32x4 mfma16(bf16x8 a, bf16x8 b, f32x4 c) {
    return __builtin_amdgcn_mfma_f32_16x16x32_bf16(a, b, c, 0, 0, 0);
}
// async global->LDS DMA, 16 B per lane; LDS dest = wave-uniform base + lane*16
static __device__ __forceinline__ void gll16(const void* g, void* l) {
    __builtin_amdgcn_global_load_lds(
        (const __attribute__((address_space(1))) unsigned int*)g,
        (__attribute__((address_space(3))) unsigned int*)l, 16, 0, 0);
}

#define LOG2E 1.44269504f

// ---------------- Kernel 1: QKV projection ----------------
// x: (2, 256, 4096) f32 ; w: (768, 256) f32
// qb[bh][n][64] linear bf16
// kb[bh][key][64] bf16, SWIZZLED: elem d stored at d ^ ((key&7)<<3)
// vt[bh][64][4096] bf16, slot-PERMUTED within 32-key groups (key 16kt+4q+r -> 8q+4kt+r)
//                        then SWIZZLED: pos p stored at p ^ ((d&7)<<3)
__global__ __launch_bounds__(256, 4) void qkv_kernel(
    const float* __restrict__ x, const float* __restrict__ w,
    __hip_bfloat16* __restrict__ qb, __hip_bfloat16* __restrict__ kb,
    __hip_bfloat16* __restrict__ vt)
{
    alignas(16) __shared__ __hip_bfloat16 sA[64 * 72];   // w tile [o][c]
    alignas(16) __shared__ __hip_bfloat16 sB[64 * 72];   // x tile transposed [n][c], c XOR-swizzled
    const int nb = blockIdx.x * 64;
    const int ob = blockIdx.y * 64;
    const int b  = blockIdx.z;
    const int tid  = threadIdx.x;
    const int lane = tid & 63;
    const int wv   = tid >> 6;
    const int quad = lane >> 4;
    const int l16  = lane & 15;

    f32x4 acc[4];
    for (int i = 0; i < 4; i++) acc[i] = (f32x4)0.f;

    for (int k0 = 0; k0 < 256; k0 += 64) {
        __syncthreads();
        {   // A: w tile, float4 loads, b128 LDS stores
            const int o = tid >> 2, c0 = (tid & 3) << 4;
            const float* srcw = w + (ob + o) * 256 + k0 + c0;
            union { bf16x8 v; __hip_bfloat16 h[8]; } u0, u1;
            #pragma unroll
            for (int i = 0; i < 2; i++) {
                float4 f = *(const float4*)(srcw + i * 4);
                u0.h[4*i+0] = __float2bfloat16(f.x); u0.h[4*i+1] = __float2bfloat16(f.y);
                u0.h[4*i+2] = __float2bfloat16(f.z); u0.h[4*i+3] = __float2bfloat16(f.w);
            }
            #pragma unroll
            for (int i = 0; i < 2; i++) {
                float4 f = *(const float4*)(srcw + 8 + i * 4);
                u1.h[4*i+0] = __float2bfloat16(f.x); u1.h[4*i+1] = __float2bfloat16(f.y);
                u1.h[4*i+2] = __float2bfloat16(f.z); u1.h[4*i+3] = __float2bfloat16(f.w);
            }
            *(bf16x8*)&sA[o * 72 + c0]     = u0.v;
            *(bf16x8*)&sA[o * 72 + c0 + 8] = u1.v;
        }
        {   // B: x tile, float4 loads, transposed scalar LDS stores (XOR-swizzled: conflict-free)
            const int c = tid >> 2, n0 = (tid & 3) << 4;
            const int csw = c ^ ((tid & 3) * 16);
            const float* srcx = x + ((size_t)b * 256 + k0 + c) * 4096 + nb + n0;
            #pragma unroll
            for (int i = 0; i < 4; i++) {
                float4 f = *(const float4*)(srcx + i * 4);
                sB[(n0 + 4*i + 0) * 72 + csw] = __float2bfloat16(f.x);
                sB[(n0 + 4*i + 1) * 72 + csw] = __float2bfloat16(f.y);
                sB[(n0 + 4*i + 2) * 72 + csw] = __float2bfloat16(f.z);
                sB[(n0 + 4*i + 3) * 72 + csw] = __float2bfloat16(f.w);
            }
        }
        __syncthreads();
        const __hip_bfloat16* aRow = &sA[(16 * wv + l16) * 72];
        #pragma unroll
        for (int ks = 0; ks < 2; ks++) {
            bf16x8 af = *(const bf16x8*)&aRow[ks * 32 + quad * 8];
            #pragma unroll
            for (int ct = 0; ct < 4; ct++) {
                bf16x8 bfv = *(const bf16x8*)&sB[(16 * ct + l16) * 72
                                                 + ((ks * 32 + quad * 8) ^ (ct * 16))];
                acc[ct] = mfma16(af, bfv, acc[ct]);
            }
        }
    }
    // ---- epilogue ----
    if (ob < 512) {
        // q/k: transpose to [n][o] in LDS, then 2 contiguous b128 stores per thread
        __syncthreads();   // all waves' MFMA reads of sA/sB done
        #pragma unroll
        for (int ct = 0; ct < 4; ct++) {
            union { short4 s; __hip_bfloat16 hh[4]; } u;
            #pragma unroll
            for (int r = 0; r < 4; r++) u.hh[r] = __float2bfloat16(acc[ct][r]);
            *(short4*)&sA[(16 * ct + l16) * 72 + 16 * wv + 4 * quad] = u.s;
        }
        __syncthreads();   // cross-wave: row n holds contributions from all 4 waves
        const int n_l = tid >> 2, d16 = (tid & 3) * 16;
        const int n = nb + n_l;
        const __hip_bfloat16* srcl = &sA[n_l * 72 + d16];
        bf16x8 v0 = *(const bf16x8*)srcl;
        bf16x8 v1 = *(const bf16x8*)(srcl + 8);
        const int bhh = b * 4 + ((ob & 255) >> 6);
        if (ob < 256) {
            __hip_bfloat16* dst = qb + ((size_t)bhh * 4096 + n) * 64;
            *(bf16x8*)(dst + d16)     = v0;
            *(bf16x8*)(dst + d16 + 8) = v1;
        } else {
            const int s = (n & 7) << 3;
            __hip_bfloat16* dst = kb + ((size_t)bhh * 4096 + n) * 64;
            *(bf16x8*)(dst + (d16 ^ s))       = v0;
            *(bf16x8*)(dst + ((d16 + 8) ^ s)) = v1;
        }
    } else {
        // v: transpose 16x64 per-wave tile through LDS, then slot-permuted + swizzled stores
        __syncthreads();   // all MFMA reads of sA/sB done
        #pragma unroll
        for (int ct = 0; ct < 4; ct++)
            #pragma unroll
            for (int r = 0; r < 4; r++)
                sA[(16 * wv + quad * 4 + r) * 72 + 16 * ct + l16] = __float2bfloat16(acc[ct][r]);
        // wave-private tile rows: in-wave RAW, no barrier needed
        int o2 = (ob - 512) + 16 * wv + l16;
        int bhh = b * 4 + (o2 >> 6), d = o2 & 63;
        const __hip_bfloat16* srcl = &sA[(16 * wv + l16) * 72 + 16 * quad];
        __hip_bfloat16* vrow = vt + ((size_t)bhh * 64 + d) * 4096;
        const int kt = quad & 1;
        const int gbase = nb + (quad >> 1) * 32;
        const int dsw = (d & 7) << 3;
        #pragma unroll
        for (int m = 0; m < 4; m++) {
            short4 val = *(const short4*)(srcl + 4 * m);
            int P4 = gbase + 8 * m + 4 * kt;          // slot-permuted position
            *(short4*)(vrow + (P4 ^ dsw)) = val;      // bank swizzle
        }
    }
}

// ---------------- Kernel 2: fused flash attention + rel-pos bias ----------------
// 8 waves = 2 q-groups x 4 key-slices. Swapped QK^T keeps P in registers.
// K/V staged by global_load_lds DMA into double-buffered linear LDS (swizzle baked
// into the global layouts). Softmax denominator computed by a ones-column MFMA
// (contracts p over the wave's 32 keys in the oacc row layout -> no shuffles).
__global__ __launch_bounds__(512, 4) void attn_kernel(
    const __hip_bfloat16* __restrict__ qb, const __hip_bfloat16* __restrict__ kb,
    const __hip_bfloat16* __restrict__ vt, const float* __restrict__ hrel,
    const float* __restrict__ wrel, float* __restrict__ out)
{
    extern __shared__ __align__(16) char smem[];         // 65536 B: 2 x (16KB K + 16KB V)
    alignas(16) __shared__ __hip_bfloat16 sRH[64 * 66];  // persistent rh bias [q][h']

    const int h    = blockIdx.x;
    const int bh   = blockIdx.y;
    const int tid  = threadIdx.x;
    const int lane = tid & 63;
    const int wv   = tid >> 6;      // 0..7
    const int qg   = wv >> 2;       // q rows qg*32..+31
    const int kg   = wv & 3;        // key slice kg*32..+31 within staged 128
    const int quad = lane >> 4;
    const int l16  = lane & 15;

    // prologue overlay
    __hip_bfloat16* sQ   = (__hip_bfloat16*)smem;            // 64x72
    __hip_bfloat16* sW   = (__hip_bfloat16*)smem + 64 * 72;  // 128x72 (wrel, row 127 zero)
    __hip_bfloat16* sHRs = (__hip_bfloat16*)smem + 192 * 72; // 64x72 (shifted hrel)
    __hip_bfloat16* sRWt = (__hip_bfloat16*)smem;            // 64x68 gather scratch

    // ---- prologue staging ----
    {   // Q: 64x64 bf16 contiguous
        int r = tid >> 3, d8 = (tid & 7) * 8;
        *(bf16x8*)&sQ[r * 72 + d8] =
            *(const bf16x8*)&qb[(((size_t)bh * 4096 + h * 64 + r)) * 64 + d8];
    }
    {   // wrel: 127x64 f32 -> bf16 (row 127 zero)
        int r = tid >> 2, c0 = (tid & 3) << 4;
        union { bf16x8 v; __hip_bfloat16 h8[8]; } u0, u1;
        #pragma unroll
        for (int i = 0; i < 2; i++) {
            float4 f = (r < 127) ? *(const float4*)&wrel[r * 64 + c0 + 4*i] : float4{0,0,0,0};
            u0.h8[4*i+0] = __float2bfloat16(f.x); u0.h8[4*i+1] = __float2bfloat16(f.y);
            u0.h8[4*i+2] = __float2bfloat16(f.z); u0.h8[4*i+3] = __float2bfloat16(f.w);
        }
        #pragma unroll
        for (int i = 0; i < 2; i++) {
            float4 f = (r < 127) ? *(const float4*)&wrel[r * 64 + c0 + 8 + 4*i] : float4{0,0,0,0};
            u1.h8[4*i+0] = __float2bfloat16(f.x); u1.h8[4*i+1] = __float2bfloat16(f.y);
            u1.h8[4*i+2] = __float2bfloat16(f.z); u1.h8[4*i+3] = __float2bfloat16(f.w);
        }
        *(bf16x8*)&sW[r * 72 + c0]     = u0.v;
        *(bf16x8*)&sW[r * 72 + c0 + 8] = u1.v;
    }
    {   // hrel rows [63-h, 127-h) -> sHRs[hp][d]
        int r = tid >> 3, c0 = (tid & 7) * 8;
        union { bf16x8 v; __hip_bfloat16 h8[8]; } u0;
        #pragma unroll
        for (int i = 0; i < 2; i++) {
            float4 f = *(const float4*)&hrel[(63 - h + r) * 64 + c0 + 4*i];
            u0.h8[4*i+0] = __float2bfloat16(f.x); u0.h8[4*i+1] = __float2bfloat16(f.y);
            u0.h8[4*i+2] = __float2bfloat16(f.z); u0.h8[4*i+3] = __float2bfloat16(f.w);
        }
        *(bf16x8*)&sHRs[r * 72 + c0] = u0.v;
    }
    __syncthreads();

    // fragments: gather frags (g-mapped) + main Q frags (qg-mapped)
    const int g    = wv & 3;
    const int half = wv >> 2;
    const __hip_bfloat16* aRow = &sQ[(16 * g + l16) * 72];
    bf16x8 qf0 = *(const bf16x8*)&aRow[quad * 8];
    bf16x8 qf1 = *(const bf16x8*)&aRow[32 + quad * 8];
    bf16x8 qm[2][2];
    #pragma unroll
    for (int qt = 0; qt < 2; qt++) {
        const __hip_bfloat16* qr = &sQ[(qg * 32 + 16 * qt + l16) * 72];
        qm[qt][0] = *(const bf16x8*)&qr[quad * 8];
        qm[qt][1] = *(const bf16x8*)&qr[32 + quad * 8];
    }
    __syncthreads();   // all frags read before sRWt overwrites sQ

    // rw gather: X[w][rr] = Q . wrel[rr]; scatter wp = rr + w - 63 -> sRWt[w][wp]
    {
        const int rbase = half * 64;
        #pragma unroll
        for (int ct = 0; ct < 4; ct++) {
            int rr = rbase + 16 * ct + l16;
            f32x4 a = (f32x4)0.f;
            a = mfma16(qf0, *(const bf16x8*)&sW[rr * 72 + quad * 8], a);
            a = mfma16(qf1, *(const bf16x8*)&sW[rr * 72 + 32 + quad * 8], a);
            #pragma unroll
            for (int r = 0; r < 4; r++) {
                int ww = 16 * g + quad * 4 + r;
                int wp = rr + ww - 63;
                if (wp >= 0 && wp < 64) sRWt[ww * 68 + wp] = __float2bfloat16(a[r]);
            }
        }
    }
    // rh bias (waves 0-3): sRH[w][h'] = Q . sHRs[h']
    if (half == 0) {
        #pragma unroll
        for (int ct = 0; ct < 4; ct++) {
            f32x4 a = (f32x4)0.f;
            a = mfma16(qf0, *(const bf16x8*)&sHRs[(16 * ct + l16) * 72 + quad * 8], a);
            a = mfma16(qf1, *(const bf16x8*)&sHRs[(16 * ct + l16) * 72 + 32 + quad * 8], a);
            #pragma unroll
            for (int r = 0; r < 4; r++)
                sRH[(16 * g + quad * 4 + r) * 66 + 16 * ct + l16] = __float2bfloat16(a[r]);
        }
    }
    __syncthreads();

    // hoist rw bias (j-invariant per wave), pre-scaled by log2(e), in f32
    union S4 { short4 s; __hip_bfloat16 h[4]; };
    float rwf[2][2][4];
    #pragma unroll
    for (int qt = 0; qt < 2; qt++)
        #pragma unroll
        for (int kt = 0; kt < 2; kt++) {
            S4 t;
            t.s = *(const short4*)&sRWt[(qg * 32 + 16 * qt + l16) * 68
                                        + 32 * (kg & 1) + 16 * kt + 4 * quad];
            #pragma unroll
            for (int r = 0; r < 4; r++)
                rwf[qt][kt][r] = LOG2E * __bfloat162float(t.h[r]);
        }
    __syncthreads();   // prologue LDS dead; DMA may now own smem

    // per-thread DMA source addresses (swizzle baked into global layout)
    const char* kT = (const char*)kb + (size_t)bh * 524288 + wv * 1024 + lane * 16;
    const char* vT = (const char*)vt + (size_t)bh * 524288
                     + (size_t)(wv * 4 + quad) * 8192 + l16 * 16;

    // stage tile 0 into buf0
    gll16(kT,           smem + wv * 1024);
    gll16(kT + 8192,    smem + 8192 + wv * 1024);
    gll16(vT,           smem + 16384 + wv * 1024);
    gll16(vT + 262144,  smem + 24576 + wv * 1024);
    __syncthreads();   // drains vmcnt: tile 0 resident

    f32x4 oacc[2][4];
    #pragma unroll
    for (int qt = 0; qt < 2; qt++)
        #pragma unroll
        for (int dt = 0; dt < 4; dt++) oacc[qt][dt] = (f32x4)0.f;
    f32x4 lacc[2] = {(f32x4)0.f, (f32x4)0.f};
    const bf16x8 vones = (bf16x8)(short)0x3F80;   // bf16 1.0 broadcast

    // fragment read offsets (XOR de-swizzle; conflict-free b128)
    const int krowOff = (kg * 32 + l16) * 128;
    const int sw  = (l16 & 7) << 4;
    const int kA  = (quad * 16) ^ sw;
    const int kB  = (64 + quad * 16) ^ sw;
    const int vOff = 16384 + l16 * 256 + ((kg * 64 + quad * 16) ^ sw);

    const __hip_bfloat16* rh0 = &sRH[(qg * 32 + l16) * 66];
    const __hip_bfloat16* rh1 = &sRH[(qg * 32 + 16 + l16) * 66];
    const float SC = 0.125f * LOG2E;

    for (int j = 0; j < 32; j++) {
        const char* buf = smem + (j & 1) * 32768;
        if (j < 31) {   // issue next-tile DMA into the other buffer (freed by last barrier)
            char* nbuf = smem + ((j + 1) & 1) * 32768;
            const char* gk = kT + (size_t)(j + 1) * 16384;
            gll16(gk,          nbuf + wv * 1024);
            gll16(gk + 8192,   nbuf + 8192 + wv * 1024);
            const char* gv = vT + (size_t)(j + 1) * 256;
            gll16(gv,          nbuf + 16384 + wv * 1024);
            gll16(gv + 262144, nbuf + 24576 + wv * 1024);
        }

        // K fragments (shared across both q-tiles)
        const char* kr = buf + krowOff;
        bf16x8 kf00 = *(const bf16x8*)(kr + kA);
        bf16x8 kf01 = *(const bf16x8*)(kr + kB);
        bf16x8 kf10 = *(const bf16x8*)(kr + 2048 + kA);
        bf16x8 kf11 = *(const bf16x8*)(kr + 2048 + kB);

        // S^T = mfma(K, Q): lane -> S[key=kg*32+16*kt+4*quad+r][q=qg*32+16*qt+l16]
        f32x4 s[2][2];
        __builtin_amdgcn_s_setprio(1);
        #pragma unroll
        for (int qt = 0; qt < 2; qt++) {
            f32x4 a0 = (f32x4)0.f, a1 = (f32x4)0.f;
            a0 = mfma16(kf00, qm[qt][0], a0);
            a0 = mfma16(kf01, qm[qt][1], a0);
            a1 = mfma16(kf10, qm[qt][0], a1);
            a1 = mfma16(kf11, qm[qt][1], a1);
            s[qt][0] = a0; s[qt][1] = a1;
        }
        __builtin_amdgcn_s_setprio(0);

        const int hp = 2 * j + (kg >> 1);
        bf16x8 pa[2];
        #pragma unroll
        for (int qt = 0; qt < 2; qt++) {
            float rhb = LOG2E * __bfloat162float((qt ? rh1 : rh0)[hp]);
            float pv[8];
            #pragma unroll
            for (int r = 0; r < 4; r++)
                pv[r] = __builtin_amdgcn_exp2f(fmaf(s[qt][0][r], SC, rwf[qt][0][r] + rhb));
            #pragma unroll
            for (int r = 0; r < 4; r++)
                pv[4 + r] = __builtin_amdgcn_exp2f(fmaf(s[qt][1][r], SC, rwf[qt][1][r] + rhb));
            union { bf16x8 v; __hip_bfloat162 b2[4]; } pu;
            #pragma unroll
            for (int pi = 0; pi < 4; pi++)
                pu.b2[pi] = __float22bfloat162_rn(float2{pv[2 * pi], pv[2 * pi + 1]});
            pa[qt] = pu.v;   // slot e=4*kt+r matches vt slot layout
        }

        // O += P V ; l += P . ones  (contracts the wave's full 32 keys)
        __builtin_amdgcn_s_setprio(1);
        #pragma unroll
        for (int dt = 0; dt < 4; dt++) {
            bf16x8 vf = *(const bf16x8*)(buf + vOff + dt * 4096);
            oacc[0][dt] = mfma16(pa[0], vf, oacc[0][dt]);
            oacc[1][dt] = mfma16(pa[1], vf, oacc[1][dt]);
        }
        lacc[0] = mfma16(pa[0], vones, lacc[0]);
        lacc[1] = mfma16(pa[1], vones, lacc[1]);
        __builtin_amdgcn_s_setprio(0);
        __syncthreads();   // drains this wave's DMA (next tile) + releases buffers
    }

    // ---- epilogue: single-round combine of the 4 key-slices ----
    // regions (kg-1) in smem: 4608 floats oacc + 64 floats lacc = 4672 each (3x = 56 KB)
    float* obuf = (float*)smem;
    if (kg != 0) {
        float* rb = obuf + (kg - 1) * 4672;
        #pragma unroll
        for (int qt = 0; qt < 2; qt++)
            #pragma unroll
            for (int dt = 0; dt < 4; dt++)
                *(f32x4*)&rb[qg * 2304 + (16 * dt + l16) * 36 + 16 * qt + 4 * quad]
                    = oacc[qt][dt];
        if (l16 == 0)
            #pragma unroll
            for (int qt = 0; qt < 2; qt++)
                #pragma unroll
                for (int r = 0; r < 4; r++)
                    rb[4608 + qg * 32 + 16 * qt + 4 * quad + r] = lacc[qt][r];
    }
    __syncthreads();
    if (kg == 0) {
        #pragma unroll
        for (int rg = 0; rg < 3; rg++) {
            const float* rb = obuf + rg * 4672;
            #pragma unroll
            for (int qt = 0; qt < 2; qt++) {
                #pragma unroll
                for (int dt = 0; dt < 4; dt++)
                    oacc[qt][dt] += *(const f32x4*)&rb[qg * 2304 + (16 * dt + l16) * 36
                                                       + 16 * qt + 4 * quad];
                #pragma unroll
                for (int r = 0; r < 4; r++)
                    lacc[qt][r] += rb[4608 + qg * 32 + 16 * qt + 4 * quad + r];
            }
        }
        const int b = bh >> 2, head = bh & 3;
        #pragma unroll
        for (int qt = 0; qt < 2; qt++) {
            f32x4 lv;
            #pragma unroll
            for (int r = 0; r < 4; r++) lv[r] = 1.f / lacc[qt][r];
            #pragma unroll
            for (int dt = 0; dt < 4; dt++) {
                f32x4 o = oacc[qt][dt] * lv;
                int dv = 16 * dt + l16;
                int q0 = qg * 32 + 16 * qt + 4 * quad;
                *(f32x4*)&out[((size_t)(b * 256 + head * 64 + dv)) * 4096 + h * 64 + q0] = o;
            }
        }
    }
}

extern "C" void kernel_launch(void* const* d_in, const int* in_sizes, int n_in,
                              void* d_out, int out_size, void* d_ws, size_t ws_size,
                              hipStream_t stream) {
    const float* x     = (const float*)d_in[0];
    const float* qkv_w = (const float*)d_in[1];
    const float* hrel  = (const float*)d_in[2];
    const float* wrel  = (const float*)d_in[3];
    float* out = (float*)d_out;

    __hip_bfloat16* qb = (__hip_bfloat16*)d_ws;
    __hip_bfloat16* kb = qb + (size_t)8 * 4096 * 64;
    __hip_bfloat16* vt = kb + (size_t)8 * 4096 * 64;

    qkv_kernel<<<dim3(64, 12, 2), 256, 0, stream>>>(x, qkv_w, qb, kb, vt);
    attn_kernel<<<dim3(64, 8), 512, 65536, stream>>>(qb, kb, vt, hrel, wrel, out);
}